// Round 1
// baseline (831.492 us; speedup 1.0000x reference)
//
#include <hip/hip_runtime.h>
#include <hip/hip_bf16.h>

// BiAttention: B=16, L=M=2048, D=1024.
// Plan:
//  conv:     Qh=f16(input*dot_scale), Kh=f16(memory), idot=input@w_in, mdot=memory@w_mem
//  tr:       Vt[b][d][m] = Kh[b][m][d]  (so GEMM2 has the same B^T structure)
//  gemm1:    S[b][l][m] = f16( Qh@Kh^T + idot[l] + mdot[m] ; masked -> -60000 )
//  softmax:  per row: rowmax, P = exp(S-m)/sum  (in place, f16); fully-masked row -> uniform (matches ref)
//  w2a:      w2[b][l] = softmax_l(rowmax)
//  o2:       o2[b][d] = sum_l w2[l]*input[b][l][d]
//  gemm2:    o1 = P@V ; epilogue writes [input | o1 | input*o1 | o2*o1]
// MFMA: mfma_f32_16x16x32_f16; A/B frag: lane holds T[row=lane&15][k=8*(lane>>4)+i] (contiguous 8);
// C/D: row=(lane>>4)*4+reg, col=lane&15 (m89-verified, dtype-independent).

#define BDIM 16
#define LDIM 2048
#define MDIM 2048
#define DDIM 1024
#define NEGF (-60000.0f)

typedef float    f32x4v __attribute__((ext_vector_type(4)));
typedef _Float16 half8  __attribute__((ext_vector_type(8)));
typedef _Float16 half4  __attribute__((ext_vector_type(4)));

// ---------------- conversion + row dots ----------------
__global__ __launch_bounds__(256) void conv_kernel(
    const float* __restrict__ input, const float* __restrict__ memory,
    const float* __restrict__ w_in, const float* __restrict__ w_mem,
    const float* __restrict__ scale,
    _Float16* __restrict__ Qh, _Float16* __restrict__ Kh,
    float* __restrict__ idot, float* __restrict__ mdot) {
  const int t = threadIdx.x, lane = t & 63, wid = t >> 6;
  const size_t row = (size_t)blockIdx.x * 4 + wid;   // over B*L rows
  const float* ir  = input  + row * DDIM;
  const float* mrp = memory + row * DDIM;
  float di = 0.f, dm = 0.f;
#pragma unroll
  for (int c = 0; c < 4; ++c) {
    const int off = c * 256 + lane * 4;
    float4 sc4 = *(const float4*)&scale[off];
    float4 wi4 = *(const float4*)&w_in[off];
    float4 wm4 = *(const float4*)&w_mem[off];
    float4 v = *(const float4*)&ir[off];
    di += v.x * wi4.x + v.y * wi4.y + v.z * wi4.z + v.w * wi4.w;
    half4 q = { (_Float16)(v.x * sc4.x), (_Float16)(v.y * sc4.y),
                (_Float16)(v.z * sc4.z), (_Float16)(v.w * sc4.w) };
    *(half4*)&Qh[row * DDIM + off] = q;
    float4 u = *(const float4*)&mrp[off];
    dm += u.x * wm4.x + u.y * wm4.y + u.z * wm4.z + u.w * wm4.w;
    half4 k = { (_Float16)u.x, (_Float16)u.y, (_Float16)u.z, (_Float16)u.w };
    *(half4*)&Kh[row * DDIM + off] = k;
  }
#pragma unroll
  for (int o = 1; o < 64; o <<= 1) {
    di += __shfl_xor(di, o, 64);
    dm += __shfl_xor(dm, o, 64);
  }
  if (lane == 0) { idot[row] = di; mdot[row] = dm; }
}

// ---------------- transpose memory (f16) -> Vt[b][d][m] ----------------
__global__ __launch_bounds__(256) void tr_kernel(const _Float16* __restrict__ Kh,
                                                 _Float16* __restrict__ Vt) {
  const int b = blockIdx.z;
  const int d0 = blockIdx.x * 64, m0 = blockIdx.y * 64;
  __shared__ _Float16 sT[64][80];   // 160B row stride: keeps 16B-aligned half8 stores
  const int t = threadIdx.x;
  {
    const int mr = t >> 2, ch = (t & 3) * 16;
    const _Float16* src = Kh + ((size_t)b * MDIM + m0 + mr) * DDIM + d0 + ch;
    *(half8*)&sT[mr][ch]     = *(const half8*)&src[0];
    *(half8*)&sT[mr][ch + 8] = *(const half8*)&src[8];
  }
  __syncthreads();
  {
    const int dr = t >> 2, mc = (t & 3) * 16;
    union { _Float16 h[16]; half8 v[2]; } tmp;
#pragma unroll
    for (int j = 0; j < 16; ++j) tmp.h[j] = sT[mc + j][dr];
    _Float16* dst = Vt + ((size_t)b * DDIM + d0 + dr) * MDIM + m0 + mc;
    *(half8*)&dst[0] = tmp.v[0];
    *(half8*)&dst[8] = tmp.v[1];
  }
}

// ---------------- GEMM1: S = Q @ K^T + dots, masked ----------------
__global__ __launch_bounds__(256) void gemm1_kernel(
    const _Float16* __restrict__ Qh, const _Float16* __restrict__ Kh,
    const float* __restrict__ idot, const float* __restrict__ mdot,
    const int* __restrict__ mask, _Float16* __restrict__ Sp) {
  const int b = blockIdx.z, bx = blockIdx.x, by = blockIdx.y;
  const int t = threadIdx.x, lane = t & 63, wid = t >> 6;
  const int wr = wid >> 1, wc = wid & 1;
  __shared__ _Float16 sA[128 * 64];
  __shared__ _Float16 sB[128 * 64];
  __shared__ float s_dl[128], s_dm[128];
  __shared__ int   s_ml[128], s_mm[128];
  if (t < 128) {
    s_dl[t] = idot[b * LDIM + by * 128 + t];
    s_ml[t] = mask[b * LDIM + by * 128 + t];
    s_dm[t] = mdot[b * MDIM + bx * 128 + t];
    s_mm[t] = mask[b * MDIM + bx * 128 + t];
  }
  const _Float16* Abase = Qh + ((size_t)b * LDIM + by * 128) * DDIM;
  const _Float16* Bbase = Kh + ((size_t)b * MDIM + bx * 128) * DDIM;
  const int srow = t >> 3;        // 0..31
  const int scol = (t & 7) * 8;   // halfs
  f32x4v acc[4][4];
#pragma unroll
  for (int i = 0; i < 4; ++i)
#pragma unroll
    for (int j = 0; j < 4; ++j) acc[i][j] = (f32x4v){0.f, 0.f, 0.f, 0.f};

  for (int ks = 0; ks < DDIM / 64; ++ks) {
    const int k0 = ks * 64;
    __syncthreads();
    half8 ta[4], tb[4];
#pragma unroll
    for (int j = 0; j < 4; ++j) {
      const int row = j * 32 + srow;
      ta[j] = *(const half8*)&Abase[(size_t)row * DDIM + k0 + scol];
      tb[j] = *(const half8*)&Bbase[(size_t)row * DDIM + k0 + scol];
    }
#pragma unroll
    for (int j = 0; j < 4; ++j) {
      const int row = j * 32 + srow;
      *(half8*)&sA[row * 64 + scol] = ta[j];
      *(half8*)&sB[row * 64 + scol] = tb[j];
    }
    __syncthreads();
#pragma unroll
    for (int kk = 0; kk < 2; ++kk) {
      const int koff = kk * 32 + (lane >> 4) * 8;
      half8 aF[4], bF[4];
#pragma unroll
      for (int i = 0; i < 4; ++i) {
        aF[i] = *(const half8*)&sA[(wr * 64 + i * 16 + (lane & 15)) * 64 + koff];
        bF[i] = *(const half8*)&sB[(wc * 64 + i * 16 + (lane & 15)) * 64 + koff];
      }
#pragma unroll
      for (int mi = 0; mi < 4; ++mi)
#pragma unroll
        for (int ni = 0; ni < 4; ++ni)
          acc[mi][ni] = __builtin_amdgcn_mfma_f32_16x16x32_f16(aF[mi], bF[ni], acc[mi][ni], 0, 0, 0);
    }
  }
  const int rb = wr * 64, cb = wc * 64;
#pragma unroll
  for (int mi = 0; mi < 4; ++mi)
#pragma unroll
    for (int ni = 0; ni < 4; ++ni)
#pragma unroll
      for (int r = 0; r < 4; ++r) {
        const int lrow = rb + mi * 16 + (lane >> 4) * 4 + r;
        const int lcol = cb + ni * 16 + (lane & 15);
        float s = acc[mi][ni][r] + s_dl[lrow] + s_dm[lcol];
        if ((s_ml[lrow] | s_mm[lcol]) != 0) s = NEGF;
        Sp[((size_t)b * LDIM + by * 128 + lrow) * MDIM + bx * 128 + lcol] = (_Float16)s;
      }
}

// ---------------- per-row softmax (in place) + rowmax ----------------
__global__ __launch_bounds__(256) void softmax_rows(_Float16* __restrict__ Sp,
                                                    float* __restrict__ rmax) {
  const int t = threadIdx.x, lane = t & 63, wid = t >> 6;
  const size_t row = (size_t)blockIdx.x * 4 + wid;
  _Float16* rp = Sp + row * (size_t)MDIM;
  float s[32];
#pragma unroll
  for (int c = 0; c < 4; ++c) {
    half8 v = *(const half8*)&rp[c * 512 + lane * 8];
#pragma unroll
    for (int j = 0; j < 8; ++j) s[c * 8 + j] = (float)v[j];
  }
  float m = -3.0e38f;
#pragma unroll
  for (int i = 0; i < 32; ++i) m = fmaxf(m, s[i]);
#pragma unroll
  for (int o = 1; o < 64; o <<= 1) m = fmaxf(m, __shfl_xor(m, o, 64));
  float sum = 0.f;
#pragma unroll
  for (int i = 0; i < 32; ++i) { s[i] = __expf(s[i] - m); sum += s[i]; }
#pragma unroll
  for (int o = 1; o < 64; o <<= 1) sum += __shfl_xor(sum, o, 64);
  const float inv = 1.f / sum;
#pragma unroll
  for (int c = 0; c < 4; ++c) {
    half8 v;
#pragma unroll
    for (int j = 0; j < 8; ++j) v[j] = (_Float16)(s[c * 8 + j] * inv);
    *(half8*)&rp[c * 512 + lane * 8] = v;
  }
  if (lane == 0) rmax[row] = m;
}

// ---------------- w2 = softmax_l(rowmax) per batch ----------------
__global__ __launch_bounds__(256) void w2a_kernel(const float* __restrict__ rmax,
                                                  float* __restrict__ w2) {
  const int b = blockIdx.x, t = threadIdx.x;
  __shared__ float red[256];
  const float* rm = rmax + (size_t)b * LDIM;
  float vals[8]; float lm = -3.0e38f;
#pragma unroll
  for (int j = 0; j < 8; ++j) { vals[j] = rm[t + j * 256]; lm = fmaxf(lm, vals[j]); }
  red[t] = lm; __syncthreads();
  for (int s = 128; s > 0; s >>= 1) {
    if (t < s) red[t] = fmaxf(red[t], red[t + s]);
    __syncthreads();
  }
  const float M = red[0]; __syncthreads();
  float ls = 0.f;
#pragma unroll
  for (int j = 0; j < 8; ++j) ls += __expf(vals[j] - M);
  red[t] = ls; __syncthreads();
  for (int s = 128; s > 0; s >>= 1) {
    if (t < s) red[t] += red[t + s];
    __syncthreads();
  }
  const float inv = 1.f / red[0];
#pragma unroll
  for (int j = 0; j < 8; ++j) w2[(size_t)b * LDIM + t + j * 256] = __expf(vals[j] - M) * inv;
}

// ---------------- o2 ----------------
__global__ void o2init_kernel(float* __restrict__ o2) {
  o2[blockIdx.x * 256 + threadIdx.x] = 0.f;
}

__global__ __launch_bounds__(256) void o2_kernel(const float* __restrict__ input,
                                                 const float* __restrict__ w2,
                                                 float* __restrict__ o2) {
  const int b = blockIdx.y, ch = blockIdx.x, t = threadIdx.x;
  __shared__ float sw[128];
  if (t < 128) sw[t] = w2[(size_t)b * LDIM + ch * 128 + t];
  __syncthreads();
  const float* ib = input + ((size_t)b * LDIM + ch * 128) * DDIM;
  float4 acc = {0.f, 0.f, 0.f, 0.f};
  for (int l = 0; l < 128; ++l) {
    const float w = sw[l];
    float4 v = *(const float4*)&ib[(size_t)l * DDIM + t * 4];
    acc.x += w * v.x; acc.y += w * v.y; acc.z += w * v.z; acc.w += w * v.w;
  }
  atomicAdd(&o2[b * DDIM + t * 4 + 0], acc.x);
  atomicAdd(&o2[b * DDIM + t * 4 + 1], acc.y);
  atomicAdd(&o2[b * DDIM + t * 4 + 2], acc.z);
  atomicAdd(&o2[b * DDIM + t * 4 + 3], acc.w);
}

// ---------------- GEMM2: o1 = P @ V, fused full epilogue ----------------
__global__ __launch_bounds__(256) void gemm2_kernel(
    const _Float16* __restrict__ Pm, const _Float16* __restrict__ Vt,
    const float* __restrict__ input, const float* __restrict__ o2,
    float* __restrict__ out) {
  const int b = blockIdx.z, bx = blockIdx.x, by = blockIdx.y;
  const int t = threadIdx.x, lane = t & 63, wid = t >> 6;
  const int wr = wid >> 1, wc = wid & 1;
  __shared__ _Float16 sA[128 * 64];
  __shared__ _Float16 sB[128 * 64];
  const _Float16* Abase = Pm + ((size_t)b * LDIM + by * 128) * MDIM;
  const _Float16* Bbase = Vt + ((size_t)b * DDIM + bx * 128) * MDIM;
  const int srow = t >> 3;
  const int scol = (t & 7) * 8;
  f32x4v acc[4][4];
#pragma unroll
  for (int i = 0; i < 4; ++i)
#pragma unroll
    for (int j = 0; j < 4; ++j) acc[i][j] = (f32x4v){0.f, 0.f, 0.f, 0.f};

  for (int ks = 0; ks < MDIM / 64; ++ks) {
    const int k0 = ks * 64;
    __syncthreads();
    half8 ta[4], tb[4];
#pragma unroll
    for (int j = 0; j < 4; ++j) {
      const int row = j * 32 + srow;
      ta[j] = *(const half8*)&Abase[(size_t)row * MDIM + k0 + scol];
      tb[j] = *(const half8*)&Bbase[(size_t)row * MDIM + k0 + scol];
    }
#pragma unroll
    for (int j = 0; j < 4; ++j) {
      const int row = j * 32 + srow;
      *(half8*)&sA[row * 64 + scol] = ta[j];
      *(half8*)&sB[row * 64 + scol] = tb[j];
    }
    __syncthreads();
#pragma unroll
    for (int kk = 0; kk < 2; ++kk) {
      const int koff = kk * 32 + (lane >> 4) * 8;
      half8 aF[4], bF[4];
#pragma unroll
      for (int i = 0; i < 4; ++i) {
        aF[i] = *(const half8*)&sA[(wr * 64 + i * 16 + (lane & 15)) * 64 + koff];
        bF[i] = *(const half8*)&sB[(wc * 64 + i * 16 + (lane & 15)) * 64 + koff];
      }
#pragma unroll
      for (int mi = 0; mi < 4; ++mi)
#pragma unroll
        for (int ni = 0; ni < 4; ++ni)
          acc[mi][ni] = __builtin_amdgcn_mfma_f32_16x16x32_f16(aF[mi], bF[ni], acc[mi][ni], 0, 0, 0);
    }
  }
  const int rb = wr * 64, cb = wc * 64;
#pragma unroll
  for (int mi = 0; mi < 4; ++mi)
#pragma unroll
    for (int ni = 0; ni < 4; ++ni)
#pragma unroll
      for (int r = 0; r < 4; ++r) {
        const int lrow = rb + mi * 16 + (lane >> 4) * 4 + r;
        const int lcol = cb + ni * 16 + (lane & 15);
        const size_t l = (size_t)by * 128 + lrow;
        const int d = bx * 128 + lcol;
        const float o1 = acc[mi][ni][r];
        const float inp = input[((size_t)b * LDIM + l) * DDIM + d];
        const float o2v = o2[b * DDIM + d];
        const size_t ob = ((size_t)b * LDIM + l) * (4 * DDIM) + d;
        out[ob] = inp;
        out[ob + DDIM] = o1;
        out[ob + 2 * DDIM] = inp * o1;
        out[ob + 3 * DDIM] = o2v * o1;
      }
}

extern "C" void kernel_launch(void* const* d_in, const int* in_sizes, int n_in,
                              void* d_out, int out_size, void* d_ws, size_t ws_size,
                              hipStream_t stream) {
  (void)in_sizes; (void)n_in; (void)out_size; (void)ws_size;
  const float* input  = (const float*)d_in[0];
  const float* memory = (const float*)d_in[1];
  const int*   mask   = (const int*)d_in[2];
  const float* w_in   = (const float*)d_in[3];
  const float* w_mem  = (const float*)d_in[4];
  const float* scale  = (const float*)d_in[5];
  float* out = (float*)d_out;

  char* p = (char*)d_ws;
  _Float16* Qh = (_Float16*)p; p += (size_t)BDIM * LDIM * DDIM * 2;   // 64 MB
  _Float16* Kh = (_Float16*)p; p += (size_t)BDIM * MDIM * DDIM * 2;   // 64 MB
  _Float16* Vt = (_Float16*)p; p += (size_t)BDIM * DDIM * MDIM * 2;   // 64 MB
  _Float16* Sp = (_Float16*)p; p += (size_t)BDIM * LDIM * MDIM * 2;   // 128 MB
  float* idot = (float*)p; p += (size_t)BDIM * LDIM * 4;
  float* mdot = (float*)p; p += (size_t)BDIM * MDIM * 4;
  float* rmax = (float*)p; p += (size_t)BDIM * LDIM * 4;
  float* w2   = (float*)p; p += (size_t)BDIM * LDIM * 4;
  float* o2   = (float*)p; p += (size_t)BDIM * DDIM * 4;

  conv_kernel<<<dim3(BDIM * LDIM / 4), dim3(256), 0, stream>>>(
      input, memory, w_in, w_mem, scale, Qh, Kh, idot, mdot);
  tr_kernel<<<dim3(DDIM / 64, MDIM / 64, BDIM), dim3(256), 0, stream>>>(Kh, Vt);
  gemm1_kernel<<<dim3(MDIM / 128, LDIM / 128, BDIM), dim3(256), 0, stream>>>(
      Qh, Kh, idot, mdot, mask, Sp);
  softmax_rows<<<dim3(BDIM * LDIM / 4), dim3(256), 0, stream>>>(Sp, rmax);
  w2a_kernel<<<dim3(BDIM), dim3(256), 0, stream>>>(rmax, w2);
  o2init_kernel<<<dim3(BDIM * DDIM / 256), dim3(256), 0, stream>>>(o2);
  o2_kernel<<<dim3(LDIM / 128, BDIM), dim3(256), 0, stream>>>(input, w2, o2);
  gemm2_kernel<<<dim3(DDIM / 128, LDIM / 128, BDIM), dim3(256), 0, stream>>>(
      Sp, Vt, input, o2, out);
}

// Round 2
// 822.567 us; speedup vs baseline: 1.0109x; 1.0109x over previous
//
#include <hip/hip_runtime.h>
#include <hip/hip_bf16.h>

// BiAttention: B=16, L=M=2048, D=1024.
//  conv:     Qh=f16(input*dot_scale), Kh=f16(memory), idot=input@w_in, mdot=memory@w_mem
//  tr:       Vt[b][d][m] = Kh[b][m][d]
//  gemm1:    S[b][l][m] = f16( Qh@Kh^T + idot[l] + mdot[m] ; masked -> -60000 )
//  softmax:  row softmax of S in place (-> P) + rowmax
//  w2a:      w2[b][l] = softmax_l(rowmax)
//  o2:       o2[b][d] = sum_l w2[l]*input[b][l][d]
//  gemm2:    o1 = P@V ; epilogue writes [input | o1 | input*o1 | o2*o1]
// R2: global_load_lds width=16 staging in both GEMMs (m151/m193: +35-67% over
// reg-staging at the 128^2 2-barrier structure) + bijective XCD swizzle (T1).
// LDS layout stays LINEAR (global_load_lds writes base+lane*16; m104).

#define BDIM 16
#define LDIM 2048
#define MDIM 2048
#define DDIM 1024
#define NEGF (-60000.0f)

typedef float    f32x4v __attribute__((ext_vector_type(4)));
typedef _Float16 half8  __attribute__((ext_vector_type(8)));
typedef _Float16 half4  __attribute__((ext_vector_type(4)));

// async global->LDS, 16B per lane; LDS dest = wave-uniform chunk base + lane*16
#define GL16(gp, lp)                                                        \
  __builtin_amdgcn_global_load_lds(                                         \
      (const __attribute__((address_space(1))) unsigned int*)(gp),          \
      (__attribute__((address_space(3))) unsigned int*)(lp), 16, 0, 0)

// ---------------- conversion + row dots ----------------
__global__ __launch_bounds__(256) void conv_kernel(
    const float* __restrict__ input, const float* __restrict__ memory,
    const float* __restrict__ w_in, const float* __restrict__ w_mem,
    const float* __restrict__ scale,
    _Float16* __restrict__ Qh, _Float16* __restrict__ Kh,
    float* __restrict__ idot, float* __restrict__ mdot) {
  const int t = threadIdx.x, lane = t & 63, wid = t >> 6;
  const size_t row = (size_t)blockIdx.x * 4 + wid;   // over B*L rows
  const float* ir  = input  + row * DDIM;
  const float* mrp = memory + row * DDIM;
  float di = 0.f, dm = 0.f;
#pragma unroll
  for (int c = 0; c < 4; ++c) {
    const int off = c * 256 + lane * 4;
    float4 sc4 = *(const float4*)&scale[off];
    float4 wi4 = *(const float4*)&w_in[off];
    float4 wm4 = *(const float4*)&w_mem[off];
    float4 v = *(const float4*)&ir[off];
    di += v.x * wi4.x + v.y * wi4.y + v.z * wi4.z + v.w * wi4.w;
    half4 q = { (_Float16)(v.x * sc4.x), (_Float16)(v.y * sc4.y),
                (_Float16)(v.z * sc4.z), (_Float16)(v.w * sc4.w) };
    *(half4*)&Qh[row * DDIM + off] = q;
    float4 u = *(const float4*)&mrp[off];
    dm += u.x * wm4.x + u.y * wm4.y + u.z * wm4.z + u.w * wm4.w;
    half4 k = { (_Float16)u.x, (_Float16)u.y, (_Float16)u.z, (_Float16)u.w };
    *(half4*)&Kh[row * DDIM + off] = k;
  }
#pragma unroll
  for (int o = 1; o < 64; o <<= 1) {
    di += __shfl_xor(di, o, 64);
    dm += __shfl_xor(dm, o, 64);
  }
  if (lane == 0) { idot[row] = di; mdot[row] = dm; }
}

// ---------------- transpose memory (f16) -> Vt[b][d][m] ----------------
__global__ __launch_bounds__(256) void tr_kernel(const _Float16* __restrict__ Kh,
                                                 _Float16* __restrict__ Vt) {
  const int b = blockIdx.z;
  const int d0 = blockIdx.x * 64, m0 = blockIdx.y * 64;
  __shared__ _Float16 sT[64][80];
  const int t = threadIdx.x;
  {
    const int mr = t >> 2, ch = (t & 3) * 16;
    const _Float16* src = Kh + ((size_t)b * MDIM + m0 + mr) * DDIM + d0 + ch;
    *(half8*)&sT[mr][ch]     = *(const half8*)&src[0];
    *(half8*)&sT[mr][ch + 8] = *(const half8*)&src[8];
  }
  __syncthreads();
  {
    const int dr = t >> 2, mc = (t & 3) * 16;
    union { _Float16 h[16]; half8 v[2]; } tmp;
#pragma unroll
    for (int j = 0; j < 16; ++j) tmp.h[j] = sT[mc + j][dr];
    _Float16* dst = Vt + ((size_t)b * DDIM + d0 + dr) * MDIM + m0 + mc;
    *(half8*)&dst[0] = tmp.v[0];
    *(half8*)&dst[8] = tmp.v[1];
  }
}

// ---------------- GEMM1: S = Q @ K^T + dots, masked ----------------
__global__ __launch_bounds__(256) void gemm1_kernel(
    const _Float16* __restrict__ Qh, const _Float16* __restrict__ Kh,
    const float* __restrict__ idot, const float* __restrict__ mdot,
    const int* __restrict__ mask, _Float16* __restrict__ Sp) {
  // bijective XCD swizzle over 1D grid (nwg = 4096, %8 == 0)
  const int id = blockIdx.x;
  const int wg = (id & 7) * ((int)gridDim.x >> 3) + (id >> 3);
  const int b = wg >> 8, rem = wg & 255, by = rem >> 4, bx = rem & 15;
  const int t = threadIdx.x, lane = t & 63, wid = t >> 6;
  const int wr = wid >> 1, wc = wid & 1;
  __shared__ _Float16 sA[128 * 64];
  __shared__ _Float16 sB[128 * 64];
  __shared__ float s_dl[128], s_dm[128];
  __shared__ int   s_ml[128], s_mm[128];
  if (t < 128) {
    s_dl[t] = idot[b * LDIM + by * 128 + t];
    s_ml[t] = mask[b * LDIM + by * 128 + t];
    s_dm[t] = mdot[b * MDIM + bx * 128 + t];
    s_mm[t] = mask[b * MDIM + bx * 128 + t];
  }
  const _Float16* Abase = Qh + ((size_t)b * LDIM + by * 128) * DDIM;
  const _Float16* Bbase = Kh + ((size_t)b * MDIM + bx * 128) * DDIM;
  const int lr = lane >> 3;          // 0..7: row within 8-row chunk
  const int lc = (lane & 7) * 8;     // half col within 64-half row
  f32x4v acc[4][4];
#pragma unroll
  for (int i = 0; i < 4; ++i)
#pragma unroll
    for (int j = 0; j < 4; ++j) acc[i][j] = (f32x4v){0.f, 0.f, 0.f, 0.f};

  for (int ks = 0; ks < DDIM / 64; ++ks) {
    const int k0 = ks * 64;
    __syncthreads();
#pragma unroll
    for (int j = 0; j < 4; ++j) {
      const int r0 = (wid * 4 + j) * 8;           // 8-row chunk base
      GL16(&Abase[(size_t)(r0 + lr) * DDIM + k0 + lc], &sA[r0 * 64]);
      GL16(&Bbase[(size_t)(r0 + lr) * DDIM + k0 + lc], &sB[r0 * 64]);
    }
    __syncthreads();
#pragma unroll
    for (int kk = 0; kk < 2; ++kk) {
      const int koff = kk * 32 + (lane >> 4) * 8;
      half8 aF[4], bF[4];
#pragma unroll
      for (int i = 0; i < 4; ++i) {
        aF[i] = *(const half8*)&sA[(wr * 64 + i * 16 + (lane & 15)) * 64 + koff];
        bF[i] = *(const half8*)&sB[(wc * 64 + i * 16 + (lane & 15)) * 64 + koff];
      }
#pragma unroll
      for (int mi = 0; mi < 4; ++mi)
#pragma unroll
        for (int ni = 0; ni < 4; ++ni)
          acc[mi][ni] = __builtin_amdgcn_mfma_f32_16x16x32_f16(aF[mi], bF[ni], acc[mi][ni], 0, 0, 0);
    }
  }
  const int rb = wr * 64, cb = wc * 64;
#pragma unroll
  for (int mi = 0; mi < 4; ++mi)
#pragma unroll
    for (int ni = 0; ni < 4; ++ni)
#pragma unroll
      for (int r = 0; r < 4; ++r) {
        const int lrow = rb + mi * 16 + (lane >> 4) * 4 + r;
        const int lcol = cb + ni * 16 + (lane & 15);
        float s = acc[mi][ni][r] + s_dl[lrow] + s_dm[lcol];
        if ((s_ml[lrow] | s_mm[lcol]) != 0) s = NEGF;
        Sp[((size_t)b * LDIM + by * 128 + lrow) * MDIM + bx * 128 + lcol] = (_Float16)s;
      }
}

// ---------------- per-row softmax (in place) + rowmax ----------------
__global__ __launch_bounds__(256) void softmax_rows(_Float16* __restrict__ Sp,
                                                    float* __restrict__ rmax) {
  const int t = threadIdx.x, lane = t & 63, wid = t >> 6;
  const size_t row = (size_t)blockIdx.x * 4 + wid;
  _Float16* rp = Sp + row * (size_t)MDIM;
  float s[32];
#pragma unroll
  for (int c = 0; c < 4; ++c) {
    half8 v = *(const half8*)&rp[c * 512 + lane * 8];
#pragma unroll
    for (int j = 0; j < 8; ++j) s[c * 8 + j] = (float)v[j];
  }
  float m = -3.0e38f;
#pragma unroll
  for (int i = 0; i < 32; ++i) m = fmaxf(m, s[i]);
#pragma unroll
  for (int o = 1; o < 64; o <<= 1) m = fmaxf(m, __shfl_xor(m, o, 64));
  float sum = 0.f;
#pragma unroll
  for (int i = 0; i < 32; ++i) { s[i] = __expf(s[i] - m); sum += s[i]; }
#pragma unroll
  for (int o = 1; o < 64; o <<= 1) sum += __shfl_xor(sum, o, 64);
  const float inv = 1.f / sum;
#pragma unroll
  for (int c = 0; c < 4; ++c) {
    half8 v;
#pragma unroll
    for (int j = 0; j < 8; ++j) v[j] = (_Float16)(s[c * 8 + j] * inv);
    *(half8*)&rp[c * 512 + lane * 8] = v;
  }
  if (lane == 0) rmax[row] = m;
}

// ---------------- w2 = softmax_l(rowmax) per batch ----------------
__global__ __launch_bounds__(256) void w2a_kernel(const float* __restrict__ rmax,
                                                  float* __restrict__ w2) {
  const int b = blockIdx.x, t = threadIdx.x;
  __shared__ float red[256];
  const float* rm = rmax + (size_t)b * LDIM;
  float vals[8]; float lm = -3.0e38f;
#pragma unroll
  for (int j = 0; j < 8; ++j) { vals[j] = rm[t + j * 256]; lm = fmaxf(lm, vals[j]); }
  red[t] = lm; __syncthreads();
  for (int s = 128; s > 0; s >>= 1) {
    if (t < s) red[t] = fmaxf(red[t], red[t + s]);
    __syncthreads();
  }
  const float M = red[0]; __syncthreads();
  float ls = 0.f;
#pragma unroll
  for (int j = 0; j < 8; ++j) ls += __expf(vals[j] - M);
  red[t] = ls; __syncthreads();
  for (int s = 128; s > 0; s >>= 1) {
    if (t < s) red[t] += red[t + s];
    __syncthreads();
  }
  const float inv = 1.f / red[0];
#pragma unroll
  for (int j = 0; j < 8; ++j) w2[(size_t)b * LDIM + t + j * 256] = __expf(vals[j] - M) * inv;
}

// ---------------- o2 ----------------
__global__ void o2init_kernel(float* __restrict__ o2) {
  o2[blockIdx.x * 256 + threadIdx.x] = 0.f;
}

__global__ __launch_bounds__(256) void o2_kernel(const float* __restrict__ input,
                                                 const float* __restrict__ w2,
                                                 float* __restrict__ o2) {
  const int b = blockIdx.y, ch = blockIdx.x, t = threadIdx.x;
  __shared__ float sw[128];
  if (t < 128) sw[t] = w2[(size_t)b * LDIM + ch * 128 + t];
  __syncthreads();
  const float* ib = input + ((size_t)b * LDIM + ch * 128) * DDIM;
  float4 acc = {0.f, 0.f, 0.f, 0.f};
  for (int l = 0; l < 128; ++l) {
    const float w = sw[l];
    float4 v = *(const float4*)&ib[(size_t)l * DDIM + t * 4];
    acc.x += w * v.x; acc.y += w * v.y; acc.z += w * v.z; acc.w += w * v.w;
  }
  atomicAdd(&o2[b * DDIM + t * 4 + 0], acc.x);
  atomicAdd(&o2[b * DDIM + t * 4 + 1], acc.y);
  atomicAdd(&o2[b * DDIM + t * 4 + 2], acc.z);
  atomicAdd(&o2[b * DDIM + t * 4 + 3], acc.w);
}

// ---------------- GEMM2: o1 = P @ V, fused full epilogue ----------------
__global__ __launch_bounds__(256) void gemm2_kernel(
    const _Float16* __restrict__ Pm, const _Float16* __restrict__ Vt,
    const float* __restrict__ input, const float* __restrict__ o2,
    float* __restrict__ out) {
  // bijective XCD swizzle over 1D grid (nwg = 2048, %8 == 0)
  const int id = blockIdx.x;
  const int wg = (id & 7) * ((int)gridDim.x >> 3) + (id >> 3);
  const int b = wg >> 7, rem = wg & 127, by = rem >> 3, bx = rem & 7;
  const int t = threadIdx.x, lane = t & 63, wid = t >> 6;
  const int wr = wid >> 1, wc = wid & 1;
  __shared__ _Float16 sA[128 * 64];
  __shared__ _Float16 sB[128 * 64];
  const _Float16* Abase = Pm + ((size_t)b * LDIM + by * 128) * MDIM;
  const _Float16* Bbase = Vt + ((size_t)b * DDIM + bx * 128) * MDIM;
  const int lr = lane >> 3;
  const int lc = (lane & 7) * 8;
  f32x4v acc[4][4];
#pragma unroll
  for (int i = 0; i < 4; ++i)
#pragma unroll
    for (int j = 0; j < 4; ++j) acc[i][j] = (f32x4v){0.f, 0.f, 0.f, 0.f};

  for (int ks = 0; ks < MDIM / 64; ++ks) {
    const int k0 = ks * 64;
    __syncthreads();
#pragma unroll
    for (int j = 0; j < 4; ++j) {
      const int r0 = (wid * 4 + j) * 8;
      GL16(&Abase[(size_t)(r0 + lr) * MDIM + k0 + lc], &sA[r0 * 64]);
      GL16(&Bbase[(size_t)(r0 + lr) * MDIM + k0 + lc], &sB[r0 * 64]);
    }
    __syncthreads();
#pragma unroll
    for (int kk = 0; kk < 2; ++kk) {
      const int koff = kk * 32 + (lane >> 4) * 8;
      half8 aF[4], bF[4];
#pragma unroll
      for (int i = 0; i < 4; ++i) {
        aF[i] = *(const half8*)&sA[(wr * 64 + i * 16 + (lane & 15)) * 64 + koff];
        bF[i] = *(const half8*)&sB[(wc * 64 + i * 16 + (lane & 15)) * 64 + koff];
      }
#pragma unroll
      for (int mi = 0; mi < 4; ++mi)
#pragma unroll
        for (int ni = 0; ni < 4; ++ni)
          acc[mi][ni] = __builtin_amdgcn_mfma_f32_16x16x32_f16(aF[mi], bF[ni], acc[mi][ni], 0, 0, 0);
    }
  }
  const int rb = wr * 64, cb = wc * 64;
#pragma unroll
  for (int mi = 0; mi < 4; ++mi)
#pragma unroll
    for (int ni = 0; ni < 4; ++ni)
#pragma unroll
      for (int r = 0; r < 4; ++r) {
        const int lrow = rb + mi * 16 + (lane >> 4) * 4 + r;
        const int lcol = cb + ni * 16 + (lane & 15);
        const size_t l = (size_t)by * 128 + lrow;
        const int d = bx * 128 + lcol;
        const float o1 = acc[mi][ni][r];
        const float inp = input[((size_t)b * LDIM + l) * DDIM + d];
        const float o2v = o2[b * DDIM + d];
        const size_t ob = ((size_t)b * LDIM + l) * (4 * DDIM) + d;
        out[ob] = inp;
        out[ob + DDIM] = o1;
        out[ob + 2 * DDIM] = inp * o1;
        out[ob + 3 * DDIM] = o2v * o1;
      }
}

extern "C" void kernel_launch(void* const* d_in, const int* in_sizes, int n_in,
                              void* d_out, int out_size, void* d_ws, size_t ws_size,
                              hipStream_t stream) {
  (void)in_sizes; (void)n_in; (void)out_size; (void)ws_size;
  const float* input  = (const float*)d_in[0];
  const float* memory = (const float*)d_in[1];
  const int*   mask   = (const int*)d_in[2];
  const float* w_in   = (const float*)d_in[3];
  const float* w_mem  = (const float*)d_in[4];
  const float* scale  = (const float*)d_in[5];
  float* out = (float*)d_out;

  char* p = (char*)d_ws;
  _Float16* Qh = (_Float16*)p; p += (size_t)BDIM * LDIM * DDIM * 2;   // 64 MB
  _Float16* Kh = (_Float16*)p; p += (size_t)BDIM * MDIM * DDIM * 2;   // 64 MB
  _Float16* Vt = (_Float16*)p; p += (size_t)BDIM * DDIM * MDIM * 2;   // 64 MB
  _Float16* Sp = (_Float16*)p; p += (size_t)BDIM * LDIM * MDIM * 2;   // 128 MB
  float* idot = (float*)p; p += (size_t)BDIM * LDIM * 4;
  float* mdot = (float*)p; p += (size_t)BDIM * MDIM * 4;
  float* rmax = (float*)p; p += (size_t)BDIM * LDIM * 4;
  float* w2   = (float*)p; p += (size_t)BDIM * LDIM * 4;
  float* o2   = (float*)p; p += (size_t)BDIM * DDIM * 4;

  conv_kernel<<<dim3(BDIM * LDIM / 4), dim3(256), 0, stream>>>(
      input, memory, w_in, w_mem, scale, Qh, Kh, idot, mdot);
  tr_kernel<<<dim3(DDIM / 64, MDIM / 64, BDIM), dim3(256), 0, stream>>>(Kh, Vt);
  gemm1_kernel<<<dim3(BDIM * 16 * 16), dim3(256), 0, stream>>>(
      Qh, Kh, idot, mdot, mask, Sp);
  softmax_rows<<<dim3(BDIM * LDIM / 4), dim3(256), 0, stream>>>(Sp, rmax);
  w2a_kernel<<<dim3(BDIM), dim3(256), 0, stream>>>(rmax, w2);
  o2init_kernel<<<dim3(BDIM * DDIM / 256), dim3(256), 0, stream>>>(o2);
  o2_kernel<<<dim3(LDIM / 128, BDIM), dim3(256), 0, stream>>>(input, w2, o2);
  gemm2_kernel<<<dim3(BDIM * 16 * 8), dim3(256), 0, stream>>>(
      Sp, Vt, input, o2, out);
}

// Round 3
// 717.234 us; speedup vs baseline: 1.1593x; 1.1469x over previous
//
#include <hip/hip_runtime.h>
#include <hip/hip_bf16.h>

// BiAttention: B=16, L=M=2048, D=1024.
//  conv -> tr -> gemm1(S=QK^T+dots,mask) -> softmax_rows -> w2a -> o2 -> gemm2(fused epilogue)
// R3: both GEMMs rebuilt as 256^2 tile / BK=64 / 8 waves (2Mx4N) / 512 thr,
// double-buffered LDS (128 KiB), counted vmcnt(8) prefetch-distance-2 pipeline,
// T2 xor-swizzle (linear GL16 dest + inverse-swizzled global src + swizzled ds_read),
// T5 setprio around MFMA quadrants.

#define BDIM 16
#define LDIM 2048
#define MDIM 2048
#define DDIM 1024
#define NEGF (-60000.0f)

typedef float    f32x4v __attribute__((ext_vector_type(4)));
typedef _Float16 half8  __attribute__((ext_vector_type(8)));
typedef _Float16 half4  __attribute__((ext_vector_type(4)));

#define GL16(gp, lp)                                                        \
  __builtin_amdgcn_global_load_lds(                                         \
      (const __attribute__((address_space(1))) unsigned int*)(gp),          \
      (__attribute__((address_space(3))) unsigned int*)(lp), 16, 0, 0)

// ---------------- conversion + row dots ----------------
__global__ __launch_bounds__(256) void conv_kernel(
    const float* __restrict__ input, const float* __restrict__ memory,
    const float* __restrict__ w_in, const float* __restrict__ w_mem,
    const float* __restrict__ scale,
    _Float16* __restrict__ Qh, _Float16* __restrict__ Kh,
    float* __restrict__ idot, float* __restrict__ mdot) {
  const int t = threadIdx.x, lane = t & 63, wid = t >> 6;
  const size_t row = (size_t)blockIdx.x * 4 + wid;
  const float* ir  = input  + row * DDIM;
  const float* mrp = memory + row * DDIM;
  float di = 0.f, dm = 0.f;
#pragma unroll
  for (int c = 0; c < 4; ++c) {
    const int off = c * 256 + lane * 4;
    float4 sc4 = *(const float4*)&scale[off];
    float4 wi4 = *(const float4*)&w_in[off];
    float4 wm4 = *(const float4*)&w_mem[off];
    float4 v = *(const float4*)&ir[off];
    di += v.x * wi4.x + v.y * wi4.y + v.z * wi4.z + v.w * wi4.w;
    half4 q = { (_Float16)(v.x * sc4.x), (_Float16)(v.y * sc4.y),
                (_Float16)(v.z * sc4.z), (_Float16)(v.w * sc4.w) };
    *(half4*)&Qh[row * DDIM + off] = q;
    float4 u = *(const float4*)&mrp[off];
    dm += u.x * wm4.x + u.y * wm4.y + u.z * wm4.z + u.w * wm4.w;
    half4 k = { (_Float16)u.x, (_Float16)u.y, (_Float16)u.z, (_Float16)u.w };
    *(half4*)&Kh[row * DDIM + off] = k;
  }
#pragma unroll
  for (int o = 1; o < 64; o <<= 1) {
    di += __shfl_xor(di, o, 64);
    dm += __shfl_xor(dm, o, 64);
  }
  if (lane == 0) { idot[row] = di; mdot[row] = dm; }
}

// ---------------- transpose memory (f16) -> Vt[b][d][m] ----------------
__global__ __launch_bounds__(256) void tr_kernel(const _Float16* __restrict__ Kh,
                                                 _Float16* __restrict__ Vt) {
  const int b = blockIdx.z;
  const int d0 = blockIdx.x * 64, m0 = blockIdx.y * 64;
  __shared__ _Float16 sT[64][80];
  const int t = threadIdx.x;
  {
    const int mr = t >> 2, ch = (t & 3) * 16;
    const _Float16* src = Kh + ((size_t)b * MDIM + m0 + mr) * DDIM + d0 + ch;
    *(half8*)&sT[mr][ch]     = *(const half8*)&src[0];
    *(half8*)&sT[mr][ch + 8] = *(const half8*)&src[8];
  }
  __syncthreads();
  {
    const int dr = t >> 2, mc = (t & 3) * 16;
    union { _Float16 h[16]; half8 v[2]; } tmp;
#pragma unroll
    for (int j = 0; j < 16; ++j) tmp.h[j] = sT[mc + j][dr];
    _Float16* dst = Vt + ((size_t)b * DDIM + d0 + dr) * MDIM + m0 + mc;
    *(half8*)&dst[0] = tmp.v[0];
    *(half8*)&dst[8] = tmp.v[1];
  }
}

// ============ 256^2 GEMM core helpers ============
// stage one 256x64 K-tile of A and B (f16, row stride `stride`), linear LDS,
// global source column pre-permuted for the read-side xor swizzle.
__device__ __forceinline__ void stage_tile(const _Float16* __restrict__ Ab,
                                           const _Float16* __restrict__ Bb,
                                           _Float16* sAb, _Float16* sBb,
                                           int stride, int wid, int lane) {
  const int r  = wid * 8 + (lane >> 3);                 // row within 64-row chunk
  const int sc = ((lane & 7) ^ (lane >> 3)) * 8;        // swizzled source col (halfs)
#pragma unroll
  for (int c = 0; c < 4; ++c) {
    GL16(Ab + (size_t)(c * 64 + r) * stride + sc, sAb + (c * 64 + wid * 8) * 64);
    GL16(Bb + (size_t)(c * 64 + r) * stride + sc, sBb + (c * 64 + wid * 8) * 64);
  }
}

// compute one 256x256x64 tile: 64 MFMA/wave, swizzled ds_reads, setprio quadrants
__device__ __forceinline__ void compute_tile(const _Float16* sAb, const _Float16* sBb,
                                             f32x4v acc[8][4], int wrow, int wcol,
                                             int lane) {
  const int l15 = lane & 15;
  int colh[2];
#pragma unroll
  for (int kk = 0; kk < 2; ++kk)
    colh[kk] = (((kk * 64) | ((lane >> 4) * 16)) ^ ((lane & 7) << 4)) >> 1;
  half8 bF[2][4];
#pragma unroll
  for (int kk = 0; kk < 2; ++kk)
#pragma unroll
    for (int n = 0; n < 4; ++n)
      bF[kk][n] = *(const half8*)&sBb[(wcol * 64 + n * 16 + l15) * 64 + colh[kk]];
#pragma unroll
  for (int q = 0; q < 4; ++q) {
    half8 aF[2][2];
#pragma unroll
    for (int kk = 0; kk < 2; ++kk)
#pragma unroll
      for (int im = 0; im < 2; ++im)
        aF[kk][im] = *(const half8*)&sAb[(wrow * 128 + (q * 2 + im) * 16 + l15) * 64 + colh[kk]];
    __builtin_amdgcn_s_setprio(1);
#pragma unroll
    for (int im = 0; im < 2; ++im)
#pragma unroll
      for (int n = 0; n < 4; ++n) {
        acc[q * 2 + im][n] = __builtin_amdgcn_mfma_f32_16x16x32_f16(
            aF[0][im], bF[0][n], acc[q * 2 + im][n], 0, 0, 0);
        acc[q * 2 + im][n] = __builtin_amdgcn_mfma_f32_16x16x32_f16(
            aF[1][im], bF[1][n], acc[q * 2 + im][n], 0, 0, 0);
      }
    __builtin_amdgcn_s_setprio(0);
  }
}

// ---------------- GEMM1: S = Q @ K^T + dots, masked (256^2 tile) ----------------
__global__ __launch_bounds__(512, 2) void gemm1_kernel(
    const _Float16* __restrict__ Qh, const _Float16* __restrict__ Kh,
    const float* __restrict__ idot, const float* __restrict__ mdot,
    const int* __restrict__ mask, _Float16* __restrict__ Sp) {
  const int id = blockIdx.x;                 // nwg = 1024, %8==0
  const int wg = (id & 7) * 128 + (id >> 3);
  const int b = wg >> 6, rem = wg & 63, by = rem >> 3, bx = rem & 7;
  const int t = threadIdx.x, lane = t & 63, wid = t >> 6;
  const int wrow = wid >> 2, wcol = wid & 3;
  __shared__ _Float16 sA[2][256 * 64];
  __shared__ _Float16 sB[2][256 * 64];
  __shared__ float s_dl[256], s_dm[256];
  __shared__ int   s_ml[256], s_mm[256];
  if (t < 256) {
    s_dl[t] = idot[b * LDIM + by * 256 + t];
    s_ml[t] = mask[b * LDIM + by * 256 + t];
    s_dm[t] = mdot[b * MDIM + bx * 256 + t];
    s_mm[t] = mask[b * MDIM + bx * 256 + t];
  }
  const _Float16* Ab = Qh + ((size_t)b * LDIM + by * 256) * DDIM;
  const _Float16* Bb = Kh + ((size_t)b * MDIM + bx * 256) * DDIM;
  constexpr int NT = DDIM / 64;              // 16
  f32x4v acc[8][4];
#pragma unroll
  for (int i = 0; i < 8; ++i)
#pragma unroll
    for (int j = 0; j < 4; ++j) acc[i][j] = (f32x4v){0.f, 0.f, 0.f, 0.f};

  stage_tile(Ab, Bb, sA[0], sB[0], DDIM, wid, lane);
  stage_tile(Ab + 64, Bb + 64, sA[1], sB[1], DDIM, wid, lane);
  asm volatile("s_waitcnt vmcnt(8) lgkmcnt(0)" ::: "memory");
  __builtin_amdgcn_s_barrier();

  for (int tt = 0; tt < NT; ++tt) {
    const int bi = tt & 1;
    compute_tile(sA[bi], sB[bi], acc, wrow, wcol, lane);
    asm volatile("s_waitcnt lgkmcnt(0)" ::: "memory");
    __builtin_amdgcn_s_barrier();
    asm volatile("" ::: "memory");
    if (tt + 2 < NT) {
      stage_tile(Ab + (tt + 2) * 64, Bb + (tt + 2) * 64, sA[bi], sB[bi], DDIM, wid, lane);
      asm volatile("s_waitcnt vmcnt(8)" ::: "memory");
    } else {
      asm volatile("s_waitcnt vmcnt(0)" ::: "memory");
    }
    __builtin_amdgcn_s_barrier();
  }

  const int rb = wrow * 128, cb = wcol * 64;
#pragma unroll
  for (int mi = 0; mi < 8; ++mi)
#pragma unroll
    for (int ni = 0; ni < 4; ++ni)
#pragma unroll
      for (int r = 0; r < 4; ++r) {
        const int lrow = rb + mi * 16 + (lane >> 4) * 4 + r;
        const int lcol = cb + ni * 16 + (lane & 15);
        float s = acc[mi][ni][r] + s_dl[lrow] + s_dm[lcol];
        if ((s_ml[lrow] | s_mm[lcol]) != 0) s = NEGF;
        Sp[((size_t)b * LDIM + by * 256 + lrow) * MDIM + bx * 256 + lcol] = (_Float16)s;
      }
}

// ---------------- per-row softmax (in place) + rowmax ----------------
__global__ __launch_bounds__(256) void softmax_rows(_Float16* __restrict__ Sp,
                                                    float* __restrict__ rmax) {
  const int t = threadIdx.x, lane = t & 63, wid = t >> 6;
  const size_t row = (size_t)blockIdx.x * 4 + wid;
  _Float16* rp = Sp + row * (size_t)MDIM;
  float s[32];
#pragma unroll
  for (int c = 0; c < 4; ++c) {
    half8 v = *(const half8*)&rp[c * 512 + lane * 8];
#pragma unroll
    for (int j = 0; j < 8; ++j) s[c * 8 + j] = (float)v[j];
  }
  float m = -3.0e38f;
#pragma unroll
  for (int i = 0; i < 32; ++i) m = fmaxf(m, s[i]);
#pragma unroll
  for (int o = 1; o < 64; o <<= 1) m = fmaxf(m, __shfl_xor(m, o, 64));
  float sum = 0.f;
#pragma unroll
  for (int i = 0; i < 32; ++i) { s[i] = __expf(s[i] - m); sum += s[i]; }
#pragma unroll
  for (int o = 1; o < 64; o <<= 1) sum += __shfl_xor(sum, o, 64);
  const float inv = 1.f / sum;
#pragma unroll
  for (int c = 0; c < 4; ++c) {
    half8 v;
#pragma unroll
    for (int j = 0; j < 8; ++j) v[j] = (_Float16)(s[c * 8 + j] * inv);
    *(half8*)&rp[c * 512 + lane * 8] = v;
  }
  if (lane == 0) rmax[row] = m;
}

// ---------------- w2 = softmax_l(rowmax) per batch ----------------
__global__ __launch_bounds__(256) void w2a_kernel(const float* __restrict__ rmax,
                                                  float* __restrict__ w2) {
  const int b = blockIdx.x, t = threadIdx.x;
  __shared__ float red[256];
  const float* rm = rmax + (size_t)b * LDIM;
  float vals[8]; float lm = -3.0e38f;
#pragma unroll
  for (int j = 0; j < 8; ++j) { vals[j] = rm[t + j * 256]; lm = fmaxf(lm, vals[j]); }
  red[t] = lm; __syncthreads();
  for (int s = 128; s > 0; s >>= 1) {
    if (t < s) red[t] = fmaxf(red[t], red[t + s]);
    __syncthreads();
  }
  const float M = red[0]; __syncthreads();
  float ls = 0.f;
#pragma unroll
  for (int j = 0; j < 8; ++j) ls += __expf(vals[j] - M);
  red[t] = ls; __syncthreads();
  for (int s = 128; s > 0; s >>= 1) {
    if (t < s) red[t] += red[t + s];
    __syncthreads();
  }
  const float inv = 1.f / red[0];
#pragma unroll
  for (int j = 0; j < 8; ++j) w2[(size_t)b * LDIM + t + j * 256] = __expf(vals[j] - M) * inv;
}

// ---------------- o2 ----------------
__global__ void o2init_kernel(float* __restrict__ o2) {
  o2[blockIdx.x * 256 + threadIdx.x] = 0.f;
}

__global__ __launch_bounds__(256) void o2_kernel(const float* __restrict__ input,
                                                 const float* __restrict__ w2,
                                                 float* __restrict__ o2) {
  const int b = blockIdx.y, ch = blockIdx.x, t = threadIdx.x;
  __shared__ float sw[128];
  if (t < 128) sw[t] = w2[(size_t)b * LDIM + ch * 128 + t];
  __syncthreads();
  const float* ib = input + ((size_t)b * LDIM + ch * 128) * DDIM;
  float4 acc = {0.f, 0.f, 0.f, 0.f};
  for (int l = 0; l < 128; ++l) {
    const float w = sw[l];
    float4 v = *(const float4*)&ib[(size_t)l * DDIM + t * 4];
    acc.x += w * v.x; acc.y += w * v.y; acc.z += w * v.z; acc.w += w * v.w;
  }
  atomicAdd(&o2[b * DDIM + t * 4 + 0], acc.x);
  atomicAdd(&o2[b * DDIM + t * 4 + 1], acc.y);
  atomicAdd(&o2[b * DDIM + t * 4 + 2], acc.z);
  atomicAdd(&o2[b * DDIM + t * 4 + 3], acc.w);
}

// ---------------- GEMM2: o1 = P @ V (256^2 tile), fused epilogue ----------------
__global__ __launch_bounds__(512, 2) void gemm2_kernel(
    const _Float16* __restrict__ Pm, const _Float16* __restrict__ Vt,
    const float* __restrict__ input, const float* __restrict__ o2,
    float* __restrict__ out) {
  const int id = blockIdx.x;                 // nwg = 512, %8==0
  const int wg = (id & 7) * 64 + (id >> 3);
  const int b = wg >> 5, rem = wg & 31, by = rem >> 2, bx = rem & 3;
  const int t = threadIdx.x, lane = t & 63, wid = t >> 6;
  const int wrow = wid >> 2, wcol = wid & 3;
  __shared__ _Float16 sA[2][256 * 64];
  __shared__ _Float16 sB[2][256 * 64];
  const _Float16* Ab = Pm + ((size_t)b * LDIM + by * 256) * MDIM;
  const _Float16* Bb = Vt + ((size_t)b * DDIM + bx * 256) * MDIM;
  constexpr int NT = MDIM / 64;              // 32
  f32x4v acc[8][4];
#pragma unroll
  for (int i = 0; i < 8; ++i)
#pragma unroll
    for (int j = 0; j < 4; ++j) acc[i][j] = (f32x4v){0.f, 0.f, 0.f, 0.f};

  stage_tile(Ab, Bb, sA[0], sB[0], MDIM, wid, lane);
  stage_tile(Ab + 64, Bb + 64, sA[1], sB[1], MDIM, wid, lane);
  asm volatile("s_waitcnt vmcnt(8) lgkmcnt(0)" ::: "memory");
  __builtin_amdgcn_s_barrier();

  for (int tt = 0; tt < NT; ++tt) {
    const int bi = tt & 1;
    compute_tile(sA[bi], sB[bi], acc, wrow, wcol, lane);
    asm volatile("s_waitcnt lgkmcnt(0)" ::: "memory");
    __builtin_amdgcn_s_barrier();
    asm volatile("" ::: "memory");
    if (tt + 2 < NT) {
      stage_tile(Ab + (tt + 2) * 64, Bb + (tt + 2) * 64, sA[bi], sB[bi], MDIM, wid, lane);
      asm volatile("s_waitcnt vmcnt(8)" ::: "memory");
    } else {
      asm volatile("s_waitcnt vmcnt(0)" ::: "memory");
    }
    __builtin_amdgcn_s_barrier();
  }

  const int rb = wrow * 128, cb = wcol * 64;
#pragma unroll
  for (int mi = 0; mi < 8; ++mi)
#pragma unroll
    for (int ni = 0; ni < 4; ++ni)
#pragma unroll
      for (int r = 0; r < 4; ++r) {
        const int lrow = rb + mi * 16 + (lane >> 4) * 4 + r;
        const int lcol = cb + ni * 16 + (lane & 15);
        const size_t l = (size_t)by * 256 + lrow;
        const int d = bx * 256 + lcol;
        const float o1 = acc[mi][ni][r];
        const float inp = input[((size_t)b * LDIM + l) * DDIM + d];
        const float o2v = o2[b * DDIM + d];
        const size_t ob = ((size_t)b * LDIM + l) * (4 * DDIM) + d;
        out[ob] = inp;
        out[ob + DDIM] = o1;
        out[ob + 2 * DDIM] = inp * o1;
        out[ob + 3 * DDIM] = o2v * o1;
      }
}

extern "C" void kernel_launch(void* const* d_in, const int* in_sizes, int n_in,
                              void* d_out, int out_size, void* d_ws, size_t ws_size,
                              hipStream_t stream) {
  (void)in_sizes; (void)n_in; (void)out_size; (void)ws_size;
  const float* input  = (const float*)d_in[0];
  const float* memory = (const float*)d_in[1];
  const int*   mask   = (const int*)d_in[2];
  const float* w_in   = (const float*)d_in[3];
  const float* w_mem  = (const float*)d_in[4];
  const float* scale  = (const float*)d_in[5];
  float* out = (float*)d_out;

  char* p = (char*)d_ws;
  _Float16* Qh = (_Float16*)p; p += (size_t)BDIM * LDIM * DDIM * 2;
  _Float16* Kh = (_Float16*)p; p += (size_t)BDIM * MDIM * DDIM * 2;
  _Float16* Vt = (_Float16*)p; p += (size_t)BDIM * DDIM * MDIM * 2;
  _Float16* Sp = (_Float16*)p; p += (size_t)BDIM * LDIM * MDIM * 2;
  float* idot = (float*)p; p += (size_t)BDIM * LDIM * 4;
  float* mdot = (float*)p; p += (size_t)BDIM * MDIM * 4;
  float* rmax = (float*)p; p += (size_t)BDIM * LDIM * 4;
  float* w2   = (float*)p; p += (size_t)BDIM * LDIM * 4;
  float* o2   = (float*)p; p += (size_t)BDIM * DDIM * 4;

  conv_kernel<<<dim3(BDIM * LDIM / 4), dim3(256), 0, stream>>>(
      input, memory, w_in, w_mem, scale, Qh, Kh, idot, mdot);
  tr_kernel<<<dim3(DDIM / 64, MDIM / 64, BDIM), dim3(256), 0, stream>>>(Kh, Vt);
  gemm1_kernel<<<dim3(BDIM * 8 * 8), dim3(512), 0, stream>>>(
      Qh, Kh, idot, mdot, mask, Sp);
  softmax_rows<<<dim3(BDIM * LDIM / 4), dim3(256), 0, stream>>>(Sp, rmax);
  w2a_kernel<<<dim3(BDIM), dim3(256), 0, stream>>>(rmax, w2);
  o2init_kernel<<<dim3(BDIM * DDIM / 256), dim3(256), 0, stream>>>(o2);
  o2_kernel<<<dim3(LDIM / 128, BDIM), dim3(256), 0, stream>>>(input, w2, o2);
  gemm2_kernel<<<dim3(BDIM * 8 * 4), dim3(512), 0, stream>>>(
      Sp, Vt, input, o2, out);
}